// Round 5
// baseline (170.834 us; speedup 1.0000x reference)
//
#include <hip/hip_runtime.h>
#include <cstdint>
#include <cstddef>

#define Bn 8192
#define Dn 1024
#define Hn 1024
#define En 8
#define MT 128                     // expert padding quantum
#define MTILE 64                   // gemm m-tile
#define NB 16                      // 64-col partial chunks per row
#define MTILES (PERM_N / MTILE)    // 144
#define PERM_N (Bn + En * MT)      // 9216
#define XBLKS ((PERM_N * Dn) / (256 * 8))   // 4608 gather blocks
#define WBLKS (16 * 16 * En)                // 2048 transpose blocks

typedef unsigned short u16;
typedef __bf16 bf16x8 __attribute__((ext_vector_type(8)));
typedef float f32x4 __attribute__((ext_vector_type(4)));
typedef unsigned short ushort8 __attribute__((ext_vector_type(8)));

// ---------- helpers ----------
__device__ __forceinline__ u16 f2bf(float f) {
  unsigned int u = __float_as_uint(f);
  unsigned int r = u + 0x7fffu + ((u >> 16) & 1u);   // RNE
  return (u16)(r >> 16);
}

__device__ __forceinline__ void gld16(const void* g, void* l) {
  __builtin_amdgcn_global_load_lds(
      (const __attribute__((address_space(1))) void*)g,
      (__attribute__((address_space(3))) void*)l, 16, 0, 0);
}

// ---------- routing: count + offsets + pad-fill + scatter, ONE block ----------
__global__ __launch_bounds__(1024) void route_k(const int* __restrict__ sidx,
                                                int* __restrict__ off,
                                                int* __restrict__ perm) {
  __shared__ int hist[16][En];
  __shared__ int base[16][En];
  __shared__ int eoff[En + 1];
  int t = threadIdx.x;
  int wv = t >> 6;
  if (t < 16 * En) ((int*)hist)[t] = 0;
#pragma unroll
  for (int i = 0; i < PERM_N / 1024; i++) perm[t + i * 1024] = -1;  // pad fill
  __syncthreads();
  int e8[8], r8[8];
#pragma unroll
  for (int i = 0; i < 8; i++) {
    int e = sidx[t + i * 1024];
    e8[i] = e;
    r8[i] = atomicAdd(&hist[wv][e], 1);
  }
  __syncthreads();
  if (t < En) {
    int s = 0;
    for (int w = 0; w < 16; w++) { base[w][t] = s; s += hist[w][t]; }
    hist[0][t] = s;
  }
  __syncthreads();
  if (t == 0) {
    int o = 0;
    for (int e = 0; e < En; e++) {
      eoff[e] = o; off[e] = o;
      o += (hist[0][e] + MT - 1) & ~(MT - 1);
    }
    eoff[En] = o; off[En] = o;
  }
  __syncthreads();
#pragma unroll
  for (int i = 0; i < 8; i++) {
    int e = e8[i];
    perm[eoff[e] + base[wv][e] + r8[i]] = t + i * 1024;
  }
}

// ---------- merged conversion: x-gather->bf16  AND  W1 transpose->bf16 ----------
__global__ __launch_bounds__(256) void cvt_k(const float* __restrict__ x,
                                             const int* __restrict__ perm,
                                             u16* __restrict__ xbp,
                                             const float* __restrict__ W1,
                                             u16* __restrict__ W1t) {
  __shared__ float tile[64][65];
  int bid = blockIdx.x;
  if (bid < XBLKS) {
    // xbp[p][:] = bf16(x[perm[p]][:]), zeros for pad
    size_t idx = ((size_t)bid * 256 + threadIdx.x) * 8;
    int p = (int)(idx >> 10);
    int col = (int)(idx & 1023);
    int tok = perm[p];
    ushort8 o;
    if (tok < 0) {
      o = (ushort8){0, 0, 0, 0, 0, 0, 0, 0};
    } else {
      const float* src = x + ((size_t)tok << 10) + col;
      float4 a = *(const float4*)src;
      float4 b = *(const float4*)(src + 4);
      o[0] = f2bf(a.x); o[1] = f2bf(a.y); o[2] = f2bf(a.z); o[3] = f2bf(a.w);
      o[4] = f2bf(b.x); o[5] = f2bf(b.y); o[6] = f2bf(b.z); o[7] = f2bf(b.w);
    }
    *(ushort8*)(xbp + idx) = o;
  } else {
    // W1 [E][D][H] fp32 -> W1t [E][H][D] bf16, 64x64 LDS tile transpose
    int wb = bid - XBLKS;
    int e = wb >> 8;
    int k0 = ((wb >> 4) & 15) * 64;   // D dim
    int n0 = (wb & 15) * 64;          // H dim
    int c4 = (threadIdx.x & 15) * 4;
    int r0 = threadIdx.x >> 4;        // 0..15
    const float* src = W1 + ((size_t)e << 20) + (size_t)k0 * Hn + n0;
#pragma unroll
    for (int i = 0; i < 4; i++) {
      int r = r0 + i * 16;
      float4 v = *(const float4*)(src + (size_t)r * Hn + c4);
      tile[r][c4 + 0] = v.x; tile[r][c4 + 1] = v.y;
      tile[r][c4 + 2] = v.z; tile[r][c4 + 3] = v.w;
    }
    __syncthreads();
    u16* dst = W1t + ((size_t)e << 20) + (size_t)n0 * Dn + k0;
#pragma unroll
    for (int i = 0; i < 4; i++) {
      int h = r0 + i * 16;
      ushort4 o;
      o.x = f2bf(tile[c4 + 0][h]);
      o.y = f2bf(tile[c4 + 1][h]);
      o.z = f2bf(tile[c4 + 2][h]);
      o.w = f2bf(tile[c4 + 3][h]);
      *(ushort4*)(dst + (size_t)h * Dn + c4) = o;
    }
  }
}

// ---------- grouped GEMM: 64x128 tile, double-buffer, 24 KB LDS (6 blk/CU) ----------
__global__ __launch_bounds__(256) void gemm_k(
    const u16* __restrict__ xbp, const u16* __restrict__ w1t,
    const float* __restrict__ b1, const float* __restrict__ w2,
    const int* __restrict__ off, float* __restrict__ partials) {
  __shared__ u16 As[2][MTILE * 32];   // 2 x 4 KB
  __shared__ u16 Bs[2][128 * 32];     // 2 x 8 KB

  int n0 = blockIdx.x * 128;          // x = n-tile: pins n-slice to one XCD
  int row0 = blockIdx.y * MTILE;
  if (row0 >= off[En]) return;
  int e = 0;
  while (row0 >= off[e + 1]) e++;     // 64-tiles never straddle experts (128-pad)

  int tid = threadIdx.x;
  int lane = tid & 63, w = tid >> 6;
  int wm = w >> 1, wn = w & 1;        // wave tile: rows 32*wm, cols 64*wn

  // staging: HW puts lane L at LDS base + L*16B -> (row L>>2, slot L&3).
  // source chunk q = slot ^ swz(row) implements the xor swizzle.
  int srow = lane >> 2;
  int slot = lane & 3;
  int scol = (slot ^ ((srow >> 1) & 3)) * 8;
  // wave w stages A rows [16w,16w+16) and B rows [32w,32w+32)
  const u16* aG = xbp + (size_t)(row0 + 16 * w + srow) * Dn + scol;
  int lOffA = (16 * w) * 32;
  const u16* bG[2];
  int lOffB[2];
#pragma unroll
  for (int j = 0; j < 2; j++) {
    int rl = 32 * w + 16 * j + srow;
    bG[j] = w1t + ((size_t)e << 20) + (size_t)(n0 + rl) * Dn + scol;
    lOffB[j] = (32 * w + 16 * j) * 32;
  }

  f32x4 acc[2][4];
#pragma unroll
  for (int i = 0; i < 2; i++)
#pragma unroll
    for (int j = 0; j < 4; j++)
      acc[i][j] = (f32x4){0.f, 0.f, 0.f, 0.f};

  int fr = lane & 15;
  int qf = lane >> 4;
  int qs = (qf ^ ((fr >> 1) & 3)) * 8;
  int offA[2], offB[4];
#pragma unroll
  for (int i = 0; i < 2; i++) offA[i] = (wm * 32 + i * 16 + fr) * 32 + qs;
#pragma unroll
  for (int j = 0; j < 4; j++) offB[j] = (wn * 64 + j * 16 + fr) * 32 + qs;

  // prefetch k=0 into buffer 0
  gld16(aG, (u16*)As[0] + lOffA);
  gld16(bG[0], (u16*)Bs[0] + lOffB[0]);
  gld16(bG[1], (u16*)Bs[0] + lOffB[1]);

  int cur = 0;
  for (int k0 = 0; k0 < Dn; k0 += 32, cur ^= 1) {
    __syncthreads();
    if (k0 + 32 < Dn) {
      int nb = cur ^ 1;
      gld16(aG + k0 + 32, (u16*)As[nb] + lOffA);
      gld16(bG[0] + k0 + 32, (u16*)Bs[nb] + lOffB[0]);
      gld16(bG[1] + k0 + 32, (u16*)Bs[nb] + lOffB[1]);
    }
    const u16* Ab = (const u16*)As[cur];
    const u16* Bb = (const u16*)Bs[cur];
    bf16x8 af[2], bfr[4];
#pragma unroll
    for (int i = 0; i < 2; i++) af[i] = *(const bf16x8*)(Ab + offA[i]);
#pragma unroll
    for (int j = 0; j < 4; j++) bfr[j] = *(const bf16x8*)(Bb + offB[j]);
#pragma unroll
    for (int i = 0; i < 2; i++)
#pragma unroll
      for (int j = 0; j < 4; j++)
        acc[i][j] = __builtin_amdgcn_mfma_f32_16x16x32_bf16(af[i], bfr[j], acc[i][j], 0, 0, 0);
  }

  // epilogue: h = relu(acc + b1); partial = h . W2[e][col][0..3]; float4 per row/chunk
  int fq = lane >> 4;
  float4 w2v[4]; float b1v[4];
#pragma unroll
  for (int j = 0; j < 4; j++) {
    int col = n0 + wn * 64 + j * 16 + fr;
    w2v[j] = *(const float4*)(w2 + ((size_t)e * Hn + col) * 4);
    b1v[j] = b1[(size_t)e * Hn + col];
  }
  int chunk = blockIdx.x * 2 + wn;    // 64-col chunk 0..15
#pragma unroll
  for (int i = 0; i < 2; i++) {
    int rbase = wm * 32 + i * 16 + fq * 4;
#pragma unroll
    for (int r = 0; r < 4; r++) {
      float s0 = 0.f, s1 = 0.f, s2 = 0.f, s3 = 0.f;
#pragma unroll
      for (int j = 0; j < 4; j++) {
        float h = acc[i][j][r] + b1v[j];
        h = fmaxf(h, 0.f);
        s0 = fmaf(h, w2v[j].x, s0);
        s1 = fmaf(h, w2v[j].y, s1);
        s2 = fmaf(h, w2v[j].z, s2);
        s3 = fmaf(h, w2v[j].w, s3);
      }
#pragma unroll
      for (int m = 1; m < 16; m <<= 1) {
        s0 += __shfl_xor(s0, m);
        s1 += __shfl_xor(s1, m);
        s2 += __shfl_xor(s2, m);
        s3 += __shfl_xor(s3, m);
      }
      if (fr == 0) {
        int row = row0 + rbase + r;
        *(float4*)(partials + ((size_t)row * NB + chunk) * 4) =
            make_float4(s0, s1, s2, s3);
      }
    }
  }
}

// ---------- reduce partials + ordinal probs ----------
__global__ void probs_k(const float* __restrict__ partials,
                        const int* __restrict__ perm, const int* __restrict__ off,
                        const int* __restrict__ sidx, const float* __restrict__ b2,
                        float* __restrict__ out) {
  int p = blockIdx.x * blockDim.x + threadIdx.x;
  if (p >= off[En]) return;
  int tok = perm[p];
  if (tok < 0) return;
  int e = sidx[tok];
  float s0 = 0.f, s1 = 0.f, s2 = 0.f, s3 = 0.f;
#pragma unroll
  for (int nb = 0; nb < NB; nb++) {
    float4 v = *(const float4*)(partials + ((size_t)p * NB + nb) * 4);
    s0 += v.x; s1 += v.y; s2 += v.z; s3 += v.w;
  }
  float l0 = s0 + b2[e * 4 + 0];
  float l1 = s1 + b2[e * 4 + 1];
  float l2 = s2 + b2[e * 4 + 2];
  float l3 = s3 + b2[e * 4 + 3];
  out[tok * 4 + 0] = l0; out[tok * 4 + 1] = l1;
  out[tok * 4 + 2] = l2; out[tok * 4 + 3] = l3;
  float q0 = 1.f / (1.f + expf(-l0));
  float q1 = 1.f / (1.f + expf(-l1));
  float q2 = 1.f / (1.f + expf(-l2));
  float q3 = 1.f / (1.f + expf(-l3));
  const float eps = 1e-8f;
  float p0 = fmaxf(1.f - q0, eps);
  float p1 = fmaxf(q0 - q1, eps);
  float p2 = fmaxf(q1 - q2, eps);
  float p3 = fmaxf(q2 - q3, eps);
  float p4 = fmaxf(q3, eps);
  float s = p0 + p1 + p2 + p3 + p4;
  float inv = 1.f / fmaxf(s, eps);
  float* pr = out + (size_t)Bn * 4 + (size_t)tok * 5;
  pr[0] = p0 * inv; pr[1] = p1 * inv; pr[2] = p2 * inv;
  pr[3] = p3 * inv; pr[4] = p4 * inv;
}

// ---------- launch ----------
extern "C" void kernel_launch(void* const* d_in, const int* in_sizes, int n_in,
                              void* d_out, int out_size, void* d_ws, size_t ws_size,
                              hipStream_t stream) {
  const float* x  = (const float*)d_in[0];
  const int* sidx = (const int*)d_in[1];
  const float* W1 = (const float*)d_in[2];
  const float* b1 = (const float*)d_in[3];
  const float* W2 = (const float*)d_in[4];
  const float* b2 = (const float*)d_in[5];
  float* out = (float*)d_out;

  uint8_t* w = (uint8_t*)d_ws;
  int* off  = (int*)(w + 64);     // 9 ints
  int* perm = (int*)(w + 512);    // 9216 ints
  u16* xbp      = (u16*)(w + 40960);                     // 18,874,368 B
  u16* w1t      = (u16*)(w + 18919424);                  // 16,777,216 B
  float* parts  = (float*)(w + 35700736);                // 2,359,296 B

  route_k<<<1, 1024, 0, stream>>>(sidx, off, perm);
  cvt_k<<<XBLKS + WBLKS, 256, 0, stream>>>(x, perm, xbp, W1, w1t);
  gemm_k<<<dim3(Hn / 128, MTILES), 256, 0, stream>>>(xbp, w1t, b1, W2, off, parts);
  probs_k<<<(PERM_N + 255) / 256, 256, 0, stream>>>(parts, perm, off, sidx, b2, out);
}